// Round 3
// baseline (334.131 us; speedup 1.0000x reference)
//
#include <hip/hip_runtime.h>

// ---- problem constants -----------------------------------------------------
#define IN_DIM   1024
#define OUT_DIM  1024
#define BATCH    4096
#define NC       8        // N_COEFFS = GRID_SIZE + SPLINE_ORDER
#define NK       12       // N_KNOTS  = GRID_SIZE + 2*SPLINE_ORDER + 1
#define KSPLINE  (IN_DIM * NC)      // 8192
#define KDIM     (KSPLINE + IN_DIM) // 9216: [spline | silu] concatenated K
#define EPS      1e-8f

typedef _Float16 f16x8 __attribute__((ext_vector_type(8)));
typedef float    f32x4 __attribute__((ext_vector_type(4)));

static __device__ __forceinline__ unsigned short f2h_bits(float f) {
  _Float16 h = (_Float16)f;
  return __builtin_bit_cast(unsigned short, h);
}

// async 16B/lane global->LDS copy; LDS dest is wave-uniform base + lane*16
static __device__ __forceinline__ void gl_lds16(const unsigned short* g, unsigned short* l) {
  __builtin_amdgcn_global_load_lds(
      (const __attribute__((address_space(1))) unsigned int*)g,
      (__attribute__((address_space(3))) unsigned int*)l, 16, 0, 0);
}

// ---- kernel 1: grid = cumsum([grid_start, softplus(grid_steps_log)]) -------
__global__ void build_grid_k(const float* __restrict__ gsl,
                             const float* __restrict__ gstart,
                             float* __restrict__ grid) {
  int i = blockIdx.x * 256 + threadIdx.x;
  if (i >= IN_DIM) return;
  float acc = gstart[i];
  grid[i * NK + 0] = acc;
#pragma unroll
  for (int t = 0; t < NK - 1; ++t) {
    float v  = gsl[i * (NK - 1) + t];
    float sp = (v > 20.f) ? v : log1pf(expf(v));  // softplus
    acc += sp;
    grid[i * NK + 1 + t] = acc;
  }
}

// ---- kernel 2: A[b, i*8..i*8+7] = bspline basis; A[b, 8192+i] = silu(x) ----
// fp32 in, f16 out; basis math in fp32 (matches np ref)
__global__ void build_A_k(const float* __restrict__ x,
                          const float* __restrict__ grid,
                          unsigned short* __restrict__ A) {
  int idx = blockIdx.x * 256 + threadIdx.x;  // b*1024 + i
  int i   = idx & (IN_DIM - 1);
  int b   = idx >> 10;
  float xv = x[idx];
  float g[NK];
#pragma unroll
  for (int t = 0; t < NK; ++t) g[t] = grid[i * NK + t];
  float bas[NK - 1];
#pragma unroll
  for (int k = 0; k < NK - 1; ++k)
    bas[k] = (xv >= g[k] && xv < g[k + 1]) ? 1.f : 0.f;
#pragma unroll
  for (int d = 1; d <= 3; ++d) {
#pragma unroll
    for (int k = 0; k < NK - 1 - d; ++k) {
      float left  = (xv - g[k])         / (g[k + d]     - g[k]     + EPS);
      float right = (g[k + d + 1] - xv) / (g[k + d + 1] - g[k + 1] + EPS);
      bas[k] = left * bas[k] + right * bas[k + 1];
    }
  }
  uint4 pack;
  pack.x = (unsigned)f2h_bits(bas[0]) | ((unsigned)f2h_bits(bas[1]) << 16);
  pack.y = (unsigned)f2h_bits(bas[2]) | ((unsigned)f2h_bits(bas[3]) << 16);
  pack.z = (unsigned)f2h_bits(bas[4]) | ((unsigned)f2h_bits(bas[5]) << 16);
  pack.w = (unsigned)f2h_bits(bas[6]) | ((unsigned)f2h_bits(bas[7]) << 16);
  *(uint4*)&A[(size_t)b * KDIM + i * NC] = pack;
  float s = xv / (1.f + expf(-xv));  // silu
  A[(size_t)b * KDIM + KSPLINE + i] = f2h_bits(s);
}

// ---- kernel 3: W[n, :8192] = coeffs[n,:], W[n, 8192:] = base_weight[n,:] ---
__global__ void build_W_k(const float* __restrict__ coeffs,
                          const float* __restrict__ bw,
                          unsigned short* __restrict__ W) {
  int idx = blockIdx.x * 256 + threadIdx.x;   // over 1024 * (9216/4)
  int n  = idx / (KDIM / 4);
  int k4 = (idx - n * (KDIM / 4)) * 4;
  float4 v;
  if (k4 < KSPLINE) v = *(const float4*)&coeffs[(size_t)n * KSPLINE + k4];
  else              v = *(const float4*)&bw[(size_t)n * IN_DIM + (k4 - KSPLINE)];
  ushort4 o;
  o.x = f2h_bits(v.x); o.y = f2h_bits(v.y); o.z = f2h_bits(v.z); o.w = f2h_bits(v.w);
  *(ushort4*)&W[(size_t)n * KDIM + k4] = o;
}

// ---- kernel 4: C = A @ W^T (f16 MFMA), epilogue += res_scale*x, fp32 out ---
// 128x128 tile, BK=64, 256 threads (4 waves), wave = 64x64 via 4x4 grid of
// 16x16x32 MFMAs. global_load_lds width 16 staging; XOR-chunk swizzle applied
// on the global side at stage time and the LDS side at read time
// (ds_read_b128 conflicts <=2-way = free).
__global__ __launch_bounds__(256) void gemm_k(const unsigned short* __restrict__ A,
                                              const unsigned short* __restrict__ W,
                                              const float* __restrict__ x,
                                              const float* __restrict__ rsp,
                                              float* __restrict__ out) {
  __shared__ __align__(16) unsigned short As[128 * 64];  // 16 KB
  __shared__ __align__(16) unsigned short Bs[128 * 64];  // 16 KB
  const int tid  = threadIdx.x;
  const int wave = tid >> 6;
  const int lane = tid & 63;
  // same-bm blocks are stride-32 apart in blockIdx -> same XCD (%8) -> A L2 reuse
  const int bm = blockIdx.x & 31;   // 32 M-blocks
  const int bn = blockIdx.x >> 5;   // 8  N-blocks
  const int l3 = lane >> 3;         // row-within-8 for staging
  const int l7 = lane & 7;          // 16B chunk for staging
  const int colsw = (l7 ^ l3) * 8;  // swizzled k-offset (elements)
  const unsigned short* aG = A + (size_t)(bm * 128 + wave * 8 + l3) * KDIM + colsw;
  const unsigned short* bG = W + (size_t)(bn * 128 + wave * 8 + l3) * KDIM + colsw;

  f32x4 acc[4][4] = {};
  const int quad = lane >> 4;
  const int r16  = lane & 15;
  const int wm   = (wave >> 1) * 64;
  const int wn   = (wave & 1) * 64;

  for (int kt = 0; kt < KDIM / 64; ++kt) {
    __syncthreads();  // prev compute done before overwriting LDS
#pragma unroll
    for (int j = 0; j < 4; ++j) {
      gl_lds16(aG + (size_t)j * 32 * KDIM, &As[(j * 4 + wave) * 512]);
      gl_lds16(bG + (size_t)j * 32 * KDIM, &Bs[(j * 4 + wave) * 512]);
    }
    __syncthreads();  // vmcnt(0) drain -> LDS tiles ready
#pragma unroll
    for (int kk = 0; kk < 2; ++kk) {
      f16x8 af[4], bf[4];
#pragma unroll
      for (int mt = 0; mt < 4; ++mt) {
        int row = wm + mt * 16 + r16;
        int col = (kk * 32 + quad * 8) ^ ((row & 7) * 8);
        af[mt] = *(const f16x8*)&As[row * 64 + col];
      }
#pragma unroll
      for (int nt = 0; nt < 4; ++nt) {
        int row = wn + nt * 16 + r16;
        int col = (kk * 32 + quad * 8) ^ ((row & 7) * 8);
        bf[nt] = *(const f16x8*)&Bs[row * 64 + col];
      }
#pragma unroll
      for (int mt = 0; mt < 4; ++mt)
#pragma unroll
        for (int nt = 0; nt < 4; ++nt)
          acc[mt][nt] = __builtin_amdgcn_mfma_f32_16x16x32_f16(af[mt], bf[nt], acc[mt][nt], 0, 0, 0);
    }
    aG += 64;
    bG += 64;
  }

  // epilogue: C/D layout col = lane&15, row = quad*4 + r (m89-verified); fp32 out
  const float rs = rsp[0];
#pragma unroll
  for (int mt = 0; mt < 4; ++mt) {
#pragma unroll
    for (int r = 0; r < 4; ++r) {
      int row = bm * 128 + wm + mt * 16 + quad * 4 + r;
      const float* xrow = x   + (size_t)row * IN_DIM;
      float*       orow = out + (size_t)row * OUT_DIM;
#pragma unroll
      for (int nt = 0; nt < 4; ++nt) {
        int col = bn * 128 + wn + nt * 16 + r16;
        orow[col] = acc[mt][nt][r] + rs * xrow[col];
      }
    }
  }
}

// ---- host-side launch ------------------------------------------------------
extern "C" void kernel_launch(void* const* d_in, const int* in_sizes, int n_in,
                              void* d_out, int out_size, void* d_ws, size_t ws_size,
                              hipStream_t stream) {
  // all inputs fp32 (per reference), output fp32
  const float* x      = (const float*)d_in[0];  // (4096, 1024)
  const float* coeffs = (const float*)d_in[1];  // (1024, 8192)
  const float* bw     = (const float*)d_in[2];  // (1024, 1024)
  const float* gsl    = (const float*)d_in[3];  // (1024, 11)
  const float* gstart = (const float*)d_in[4];  // (1024, 1)
  const float* rsp    = (const float*)d_in[5];  // (1,)

  char* ws = (char*)d_ws;
  float*          grid = (float*)ws;                                   // 48 KB
  unsigned short* A    = (unsigned short*)(ws + 65536);                // 75.5 MB f16
  unsigned short* W    = (unsigned short*)(ws + 65536 + (size_t)BATCH * KDIM * 2); // 18.9 MB f16
  float*          out  = (float*)d_out;                                // fp32

  build_grid_k<<<4, 256, 0, stream>>>(gsl, gstart, grid);
  build_A_k<<<(BATCH * IN_DIM) / 256, 256, 0, stream>>>(x, grid, A);
  build_W_k<<<(OUT_DIM * (KDIM / 4)) / 256, 256, 0, stream>>>(coeffs, bw, W);
  gemm_k<<<256, 256, 0, stream>>>(A, W, x, rsp, out);
}

// Round 4
// 262.594 us; speedup vs baseline: 1.2724x; 1.2724x over previous
//
#include <hip/hip_runtime.h>

// ---- problem constants -----------------------------------------------------
#define IN_DIM   1024
#define OUT_DIM  1024
#define BATCH    4096
#define NC       8        // N_COEFFS
#define NK       12       // N_KNOTS
#define KSPLINE  (IN_DIM * NC)      // 8192
#define KDIM     (KSPLINE + IN_DIM) // 9216
#define EPS      1e-8f
#define KSPLIT   4
#define KT_PER   (KDIM / 64 / KSPLIT)  // 36 k-iterations per split block

typedef _Float16 f16x8 __attribute__((ext_vector_type(8)));
typedef float    f32x4 __attribute__((ext_vector_type(4)));

static __device__ __forceinline__ unsigned short f2h_bits(float f) {
  _Float16 h = (_Float16)f;
  return __builtin_bit_cast(unsigned short, h);
}

// async 16B/lane global->LDS copy; LDS dest is wave-uniform base + lane*16
static __device__ __forceinline__ void gl_lds16(const unsigned short* g, unsigned short* l) {
  __builtin_amdgcn_global_load_lds(
      (const __attribute__((address_space(1))) unsigned int*)g,
      (__attribute__((address_space(3))) unsigned int*)l, 16, 0, 0);
}

// ---- kernel 1: grid rows + reciprocal tables -------------------------------
// rtab row (32 floats): [0..10]=1/(g[j+1]-g[j]+EPS), [11..20]=1/(g[j+2]-g[j]+EPS),
// [21..29]=1/(g[j+3]-g[j]+EPS)  (divides done ONCE per i, not per (b,i))
__global__ void build_grid_k(const float* __restrict__ gsl,
                             const float* __restrict__ gstart,
                             float* __restrict__ grid,
                             float* __restrict__ rtab) {
  int i = blockIdx.x * 256 + threadIdx.x;
  if (i >= IN_DIM) return;
  float g[NK];
  float acc = gstart[i];
  g[0] = acc;
#pragma unroll
  for (int t = 0; t < NK - 1; ++t) {
    float v  = gsl[i * (NK - 1) + t];
    float sp = (v > 20.f) ? v : log1pf(expf(v));  // softplus
    acc += sp;
    g[t + 1] = acc;
  }
#pragma unroll
  for (int t = 0; t < NK; ++t) grid[i * NK + t] = g[t];
  float* r = rtab + i * 32;
#pragma unroll
  for (int j = 0; j < 11; ++j) r[j]      = 1.f / (g[j + 1] - g[j] + EPS);
#pragma unroll
  for (int j = 0; j < 10; ++j) r[11 + j] = 1.f / (g[j + 2] - g[j] + EPS);
#pragma unroll
  for (int j = 0; j <  9; ++j) r[21 + j] = 1.f / (g[j + 3] - g[j] + EPS);
}

// ---- kernel 2: A[b, i*8..+7] = cubic B-spline basis; A[b, 8192+i] = silu ---
// block = 256 consecutive i, loops over 16 b rows; tables live in registers
__global__ void build_A_k(const float* __restrict__ x,
                          const float* __restrict__ grid,
                          const float* __restrict__ rtab,
                          unsigned short* __restrict__ A) {
  const int i  = (blockIdx.x & 3) * 256 + threadIdx.x;
  const int b0 = (blockIdx.x >> 2) * 16;
  float g[NK], r[30];
#pragma unroll
  for (int t = 0; t < NK; ++t) g[t] = grid[i * NK + t];
  const float* rt = rtab + i * 32;
#pragma unroll
  for (int t = 0; t < 30; ++t) r[t] = rt[t];

  for (int bb = 0; bb < 16; ++bb) {
    const int b = b0 + bb;
    float xv = x[(size_t)b * IN_DIM + i];
    float bas[NK - 1];
#pragma unroll
    for (int k = 0; k < NK - 1; ++k)
      bas[k] = (xv >= g[k] && xv < g[k + 1]) ? 1.f : 0.f;
    const int off[3] = {0, 11, 21};
#pragma unroll
    for (int d = 1; d <= 3; ++d) {
#pragma unroll
      for (int k = 0; k < NK - 1 - d; ++k) {
        float left  = (xv - g[k])         * r[off[d - 1] + k];
        float right = (g[k + d + 1] - xv) * r[off[d - 1] + k + 1];
        bas[k] = left * bas[k] + right * bas[k + 1];
      }
    }
    uint4 pack;
    pack.x = (unsigned)f2h_bits(bas[0]) | ((unsigned)f2h_bits(bas[1]) << 16);
    pack.y = (unsigned)f2h_bits(bas[2]) | ((unsigned)f2h_bits(bas[3]) << 16);
    pack.z = (unsigned)f2h_bits(bas[4]) | ((unsigned)f2h_bits(bas[5]) << 16);
    pack.w = (unsigned)f2h_bits(bas[6]) | ((unsigned)f2h_bits(bas[7]) << 16);
    *(uint4*)&A[(size_t)b * KDIM + i * NC] = pack;
    float s = xv / (1.f + expf(-xv));  // silu (one divide per (b,i), ok)
    A[(size_t)b * KDIM + KSPLINE + i] = f2h_bits(s);
  }
}

// ---- kernel 3: W[n, :8192]=f16(coeffs[n,:]), W[n, 8192:]=f16(bw[n,:]) ------
__global__ void build_W_k(const float* __restrict__ coeffs,
                          const float* __restrict__ bw,
                          unsigned short* __restrict__ W) {
  int idx = blockIdx.x * 256 + threadIdx.x;   // over 1024 * (9216/4)
  int n  = idx / (KDIM / 4);
  int k4 = (idx - n * (KDIM / 4)) * 4;
  float4 v;
  if (k4 < KSPLINE) v = *(const float4*)&coeffs[(size_t)n * KSPLINE + k4];
  else              v = *(const float4*)&bw[(size_t)n * IN_DIM + (k4 - KSPLINE)];
  ushort4 o;
  o.x = f2h_bits(v.x); o.y = f2h_bits(v.y); o.z = f2h_bits(v.z); o.w = f2h_bits(v.w);
  *(ushort4*)&W[(size_t)n * KDIM + k4] = o;
}

// ---- kernel 4: out = res_scale * x (base for gemm's atomic accumulation) ---
__global__ void init_out_k(const float* __restrict__ x,
                           const float* __restrict__ rsp,
                           float* __restrict__ out) {
  int j = (blockIdx.x * 256 + threadIdx.x) * 4;
  const float rs = rsp[0];
  float4 v = *(const float4*)&x[j];
  float4 o;
  o.x = rs * v.x; o.y = rs * v.y; o.z = rs * v.z; o.w = rs * v.w;
  *(float4*)&out[j] = o;
}

// ---- kernel 5: out += A @ W^T (f16 MFMA), K-split x4, atomic epilogue ------
// 128x128 tile, BK=64, 256 threads (4 waves), 1024 blocks -> 4 blocks/CU so
// independent blocks cover each other's barrier/vmcnt(0) drains (m114).
__global__ __launch_bounds__(256) void gemm_k(const unsigned short* __restrict__ A,
                                              const unsigned short* __restrict__ W,
                                              float* __restrict__ out) {
  __shared__ __align__(16) unsigned short As[128 * 64];  // 16 KB
  __shared__ __align__(16) unsigned short Bs[128 * 64];  // 16 KB
  const int tid  = threadIdx.x;
  const int wave = tid >> 6;
  const int lane = tid & 63;
  const int ks = blockIdx.x >> 8;        // K-split slice 0..3
  const int t  = blockIdx.x & 255;
  const int bm = t & 31;                 // same-bm blocks stride 32 -> same XCD
  const int bn = t >> 5;
  const int l3 = lane >> 3;              // row-within-8 for staging
  const int l7 = lane & 7;               // 16B chunk for staging
  const int colsw = (l7 ^ l3) * 8;       // XOR-swizzled k-offset (elements)
  const unsigned short* aG = A + (size_t)(bm * 128 + wave * 8 + l3) * KDIM + colsw
                               + (size_t)ks * (KT_PER * 64);
  const unsigned short* bG = W + (size_t)(bn * 128 + wave * 8 + l3) * KDIM + colsw
                               + (size_t)ks * (KT_PER * 64);

  f32x4 acc[4][4] = {};
  const int quad = lane >> 4;
  const int r16  = lane & 15;
  const int wm   = (wave >> 1) * 64;
  const int wn   = (wave & 1) * 64;

  for (int kt = 0; kt < KT_PER; ++kt) {
    __syncthreads();  // prev compute done before overwriting LDS
#pragma unroll
    for (int j = 0; j < 4; ++j) {
      gl_lds16(aG + (size_t)j * 32 * KDIM, &As[(j * 4 + wave) * 512]);
      gl_lds16(bG + (size_t)j * 32 * KDIM, &Bs[(j * 4 + wave) * 512]);
    }
    __syncthreads();  // vmcnt(0) drain -> LDS tiles ready
#pragma unroll
    for (int kk = 0; kk < 2; ++kk) {
      f16x8 af[4], bf[4];
#pragma unroll
      for (int mt = 0; mt < 4; ++mt) {
        int row = wm + mt * 16 + r16;
        int col = (kk * 32 + quad * 8) ^ ((row & 7) * 8);
        af[mt] = *(const f16x8*)&As[row * 64 + col];
      }
#pragma unroll
      for (int nt = 0; nt < 4; ++nt) {
        int row = wn + nt * 16 + r16;
        int col = (kk * 32 + quad * 8) ^ ((row & 7) * 8);
        bf[nt] = *(const f16x8*)&Bs[row * 64 + col];
      }
#pragma unroll
      for (int mt = 0; mt < 4; ++mt)
#pragma unroll
        for (int nt = 0; nt < 4; ++nt)
          acc[mt][nt] = __builtin_amdgcn_mfma_f32_16x16x32_f16(af[mt], bf[nt], acc[mt][nt], 0, 0, 0);
    }
    aG += 64;
    bG += 64;
  }

  // epilogue: C/D layout col = lane&15, row = quad*4 + r; atomic K-split sum
#pragma unroll
  for (int mt = 0; mt < 4; ++mt) {
#pragma unroll
    for (int r = 0; r < 4; ++r) {
      int row = bm * 128 + wm + mt * 16 + quad * 4 + r;
      float* orow = out + (size_t)row * OUT_DIM;
#pragma unroll
      for (int nt = 0; nt < 4; ++nt) {
        int col = bn * 128 + wn + nt * 16 + r16;
        atomicAdd(&orow[col], acc[mt][nt][r]);
      }
    }
  }
}

// ---- host-side launch ------------------------------------------------------
extern "C" void kernel_launch(void* const* d_in, const int* in_sizes, int n_in,
                              void* d_out, int out_size, void* d_ws, size_t ws_size,
                              hipStream_t stream) {
  const float* x      = (const float*)d_in[0];  // (4096, 1024) fp32
  const float* coeffs = (const float*)d_in[1];  // (1024, 8192)
  const float* bw     = (const float*)d_in[2];  // (1024, 1024)
  const float* gsl    = (const float*)d_in[3];  // (1024, 11)
  const float* gstart = (const float*)d_in[4];  // (1024, 1)
  const float* rsp    = (const float*)d_in[5];  // (1,)

  // ws: A (75.5 MB f16) then W (18.9 MB f16). grid+rtab tables live in the
  // head of d_out (176 KB of 16.8 MB) — consumed by build_A, then overwritten
  // by init_out before gemm accumulates.
  char* ws = (char*)d_ws;
  unsigned short* A    = (unsigned short*)ws;
  unsigned short* W    = (unsigned short*)(ws + (size_t)BATCH * KDIM * 2);
  float*          out  = (float*)d_out;
  float*          grid = out;                    // 12288 floats
  float*          rtab = out + 16384;            // 32768 floats

  build_grid_k<<<4, 256, 0, stream>>>(gsl, gstart, grid, rtab);
  build_A_k<<<(IN_DIM / 256) * (BATCH / 16), 256, 0, stream>>>(x, grid, rtab, A);
  build_W_k<<<(OUT_DIM * (KDIM / 4)) / 256, 256, 0, stream>>>(coeffs, bw, W);
  init_out_k<<<(BATCH * OUT_DIM) / (256 * 4), 256, 0, stream>>>(x, rsp, out);
  gemm_k<<<256 * KSPLIT, 256, 0, stream>>>(A, W, out);
}

// Round 5
// 260.556 us; speedup vs baseline: 1.2824x; 1.0078x over previous
//
#include <hip/hip_runtime.h>

// ---- problem constants -----------------------------------------------------
#define IN_DIM   1024
#define OUT_DIM  1024
#define BATCH    4096
#define NC       8        // N_COEFFS
#define NK       12       // N_KNOTS
#define KSPLINE  (IN_DIM * NC)      // 8192
#define KDIM     (KSPLINE + IN_DIM) // 9216
#define EPS      1e-8f
#define KSPLIT   4
#define KT_PER   (KDIM / 64 / KSPLIT)  // 36 k-iterations per split block

typedef _Float16 f16x8 __attribute__((ext_vector_type(8)));
typedef float    f32x4 __attribute__((ext_vector_type(4)));

static __device__ __forceinline__ unsigned short f2h_bits(float f) {
  _Float16 h = (_Float16)f;
  return __builtin_bit_cast(unsigned short, h);
}

// async 16B/lane global->LDS copy; LDS dest is wave-uniform base + lane*16
static __device__ __forceinline__ void gl_lds16(const unsigned short* g, unsigned short* l) {
  __builtin_amdgcn_global_load_lds(
      (const __attribute__((address_space(1))) unsigned int*)g,
      (__attribute__((address_space(3))) unsigned int*)l, 16, 0, 0);
}

// ---- kernel 1: TRANSPOSED grid rows + reciprocal tables --------------------
// gT[t*1024+i] = knot t of input-dim i; rT[t*1024+i]:
//   t=0..10 : 1/(g[t+1]-g[t]+EPS), t=11..20 : 1/(g[t-11+2]-g[t-11]+EPS),
//   t=21..29: 1/(g[t-21+3]-g[t-21]+EPS)
// Transposed so build_A's per-lane table loads are stride-1 across lanes
// (one 256B coalesced read per load instr instead of a 48-128 cacheline gather).
__global__ void build_grid_k(const float* __restrict__ gsl,
                             const float* __restrict__ gstart,
                             float* __restrict__ gT,
                             float* __restrict__ rT) {
  int i = blockIdx.x * 256 + threadIdx.x;
  if (i >= IN_DIM) return;
  float g[NK];
  float acc = gstart[i];
  g[0] = acc;
#pragma unroll
  for (int t = 0; t < NK - 1; ++t) {
    float v  = gsl[i * (NK - 1) + t];
    float sp = (v > 20.f) ? v : log1pf(expf(v));  // softplus
    acc += sp;
    g[t + 1] = acc;
  }
#pragma unroll
  for (int t = 0; t < NK; ++t) gT[t * IN_DIM + i] = g[t];
#pragma unroll
  for (int j = 0; j < 11; ++j) rT[(j)      * IN_DIM + i] = 1.f / (g[j + 1] - g[j] + EPS);
#pragma unroll
  for (int j = 0; j < 10; ++j) rT[(11 + j) * IN_DIM + i] = 1.f / (g[j + 2] - g[j] + EPS);
#pragma unroll
  for (int j = 0; j <  9; ++j) rT[(21 + j) * IN_DIM + i] = 1.f / (g[j + 3] - g[j] + EPS);
}

// ---- kernel 2: A[b, i*8..+7] = cubic B-spline basis; A[b, 8192+i] = silu ---
// Also fuses out[b,i] = res_scale * x[b,i] (the gemm atomics accumulate on top).
// Thread = one i, 16 consecutive b rows; tables in registers (launch_bounds
// guarantees a 256-VGPR budget -> no spill).
__global__ __launch_bounds__(256, 2) void build_A_k(const float* __restrict__ x,
                                                    const float* __restrict__ gT,
                                                    const float* __restrict__ rT,
                                                    const float* __restrict__ rsp,
                                                    unsigned short* __restrict__ A,
                                                    float* __restrict__ out) {
  const int i  = (blockIdx.x & 3) * 256 + threadIdx.x;
  const int b0 = (blockIdx.x >> 2) * 16;
  const float rs = rsp[0];
  float g[NK], r[30];
#pragma unroll
  for (int t = 0; t < NK; ++t) g[t] = gT[t * IN_DIM + i];   // coalesced
#pragma unroll
  for (int t = 0; t < 30; ++t) r[t] = rT[t * IN_DIM + i];   // coalesced

  for (int bb = 0; bb < 16; ++bb) {
    const int b = b0 + bb;
    float xv = x[(size_t)b * IN_DIM + i];
    float bas[NK - 1];
#pragma unroll
    for (int k = 0; k < NK - 1; ++k)
      bas[k] = (xv >= g[k] && xv < g[k + 1]) ? 1.f : 0.f;
    const int off[3] = {0, 11, 21};
#pragma unroll
    for (int d = 1; d <= 3; ++d) {
#pragma unroll
      for (int k = 0; k < NK - 1 - d; ++k) {
        float left  = (xv - g[k])         * r[off[d - 1] + k];
        float right = (g[k + d + 1] - xv) * r[off[d - 1] + k + 1];
        bas[k] = left * bas[k] + right * bas[k + 1];
      }
    }
    uint4 pack;
    pack.x = (unsigned)f2h_bits(bas[0]) | ((unsigned)f2h_bits(bas[1]) << 16);
    pack.y = (unsigned)f2h_bits(bas[2]) | ((unsigned)f2h_bits(bas[3]) << 16);
    pack.z = (unsigned)f2h_bits(bas[4]) | ((unsigned)f2h_bits(bas[5]) << 16);
    pack.w = (unsigned)f2h_bits(bas[6]) | ((unsigned)f2h_bits(bas[7]) << 16);
    *(uint4*)&A[(size_t)b * KDIM + i * NC] = pack;
    float s = xv / (1.f + expf(-xv));  // silu
    A[(size_t)b * KDIM + KSPLINE + i] = f2h_bits(s);
    out[(size_t)b * OUT_DIM + i] = rs * xv;  // fused init_out
  }
}

// ---- kernel 3: W[n, :8192]=f16(coeffs[n,:]), W[n, 8192:]=f16(bw[n,:]) ------
__global__ void build_W_k(const float* __restrict__ coeffs,
                          const float* __restrict__ bw,
                          unsigned short* __restrict__ W) {
  int idx = blockIdx.x * 256 + threadIdx.x;   // over 1024 * (9216/4)
  int n  = idx / (KDIM / 4);
  int k4 = (idx - n * (KDIM / 4)) * 4;
  float4 v;
  if (k4 < KSPLINE) v = *(const float4*)&coeffs[(size_t)n * KSPLINE + k4];
  else              v = *(const float4*)&bw[(size_t)n * IN_DIM + (k4 - KSPLINE)];
  ushort4 o;
  o.x = f2h_bits(v.x); o.y = f2h_bits(v.y); o.z = f2h_bits(v.z); o.w = f2h_bits(v.w);
  *(ushort4*)&W[(size_t)n * KDIM + k4] = o;
}

// ---- kernel 4: out += A @ W^T (f16 MFMA), K-split x4, atomic epilogue ------
// 128x128 tile, BK=64, 256 threads (4 waves), 1024 blocks -> 4 blocks/CU.
__global__ __launch_bounds__(256) void gemm_k(const unsigned short* __restrict__ A,
                                              const unsigned short* __restrict__ W,
                                              float* __restrict__ out) {
  __shared__ __align__(16) unsigned short As[128 * 64];  // 16 KB
  __shared__ __align__(16) unsigned short Bs[128 * 64];  // 16 KB
  const int tid  = threadIdx.x;
  const int wave = tid >> 6;
  const int lane = tid & 63;
  const int ks = blockIdx.x >> 8;        // K-split slice 0..3
  const int t  = blockIdx.x & 255;
  const int bm = t & 31;                 // same-bm blocks stride 32 -> same XCD
  const int bn = t >> 5;
  const int l3 = lane >> 3;              // row-within-8 for staging
  const int l7 = lane & 7;               // 16B chunk for staging
  const int colsw = (l7 ^ l3) * 8;       // XOR-swizzled k-offset (elements)
  const unsigned short* aG = A + (size_t)(bm * 128 + wave * 8 + l3) * KDIM + colsw
                               + (size_t)ks * (KT_PER * 64);
  const unsigned short* bG = W + (size_t)(bn * 128 + wave * 8 + l3) * KDIM + colsw
                               + (size_t)ks * (KT_PER * 64);

  f32x4 acc[4][4] = {};
  const int quad = lane >> 4;
  const int r16  = lane & 15;
  const int wm   = (wave >> 1) * 64;
  const int wn   = (wave & 1) * 64;

  for (int kt = 0; kt < KT_PER; ++kt) {
    __syncthreads();  // prev compute done before overwriting LDS
#pragma unroll
    for (int j = 0; j < 4; ++j) {
      gl_lds16(aG + (size_t)j * 32 * KDIM, &As[(j * 4 + wave) * 512]);
      gl_lds16(bG + (size_t)j * 32 * KDIM, &Bs[(j * 4 + wave) * 512]);
    }
    __syncthreads();  // vmcnt(0) drain -> LDS tiles ready
#pragma unroll
    for (int kk = 0; kk < 2; ++kk) {
      f16x8 af[4], bf[4];
#pragma unroll
      for (int mt = 0; mt < 4; ++mt) {
        int row = wm + mt * 16 + r16;
        int col = (kk * 32 + quad * 8) ^ ((row & 7) * 8);
        af[mt] = *(const f16x8*)&As[row * 64 + col];
      }
#pragma unroll
      for (int nt = 0; nt < 4; ++nt) {
        int row = wn + nt * 16 + r16;
        int col = (kk * 32 + quad * 8) ^ ((row & 7) * 8);
        bf[nt] = *(const f16x8*)&Bs[row * 64 + col];
      }
#pragma unroll
      for (int mt = 0; mt < 4; ++mt)
#pragma unroll
        for (int nt = 0; nt < 4; ++nt)
          acc[mt][nt] = __builtin_amdgcn_mfma_f32_16x16x32_f16(af[mt], bf[nt], acc[mt][nt], 0, 0, 0);
    }
    aG += 64;
    bG += 64;
  }

  // epilogue: C/D layout col = lane&15, row = quad*4 + r; atomic K-split sum
#pragma unroll
  for (int mt = 0; mt < 4; ++mt) {
#pragma unroll
    for (int r = 0; r < 4; ++r) {
      int row = bm * 128 + wm + mt * 16 + quad * 4 + r;
      float* orow = out + (size_t)row * OUT_DIM;
#pragma unroll
      for (int nt = 0; nt < 4; ++nt) {
        int col = bn * 128 + wn + nt * 16 + r16;
        atomicAdd(&orow[col], acc[mt][nt][r]);
      }
    }
  }
}

// ---- host-side launch ------------------------------------------------------
extern "C" void kernel_launch(void* const* d_in, const int* in_sizes, int n_in,
                              void* d_out, int out_size, void* d_ws, size_t ws_size,
                              hipStream_t stream) {
  const float* x      = (const float*)d_in[0];  // (4096, 1024) fp32
  const float* coeffs = (const float*)d_in[1];  // (1024, 8192)
  const float* bw     = (const float*)d_in[2];  // (1024, 1024)
  const float* gsl    = (const float*)d_in[3];  // (1024, 11)
  const float* gstart = (const float*)d_in[4];  // (1024, 1)
  const float* rsp    = (const float*)d_in[5];  // (1,)

  // ws layout: A (75.5 MB f16) | W (18.9 MB f16). The transposed tables
  // (168 KB) live at the HEAD OF THE W REGION: build_grid writes them,
  // build_A consumes them, THEN build_W overwrites that memory (stream order
  // guarantees safety). Total ws use = 94.4 MB (<= round-3's proven 94.5).
  char* ws = (char*)d_ws;
  unsigned short* A  = (unsigned short*)ws;
  unsigned short* W  = (unsigned short*)(ws + (size_t)BATCH * KDIM * 2);
  float*          gT = (float*)W;                  // 12*1024 floats
  float*          rT = gT + 12 * IN_DIM;           // 30*1024 floats
  float*          out = (float*)d_out;

  build_grid_k<<<4, 256, 0, stream>>>(gsl, gstart, gT, rT);
  build_A_k<<<(IN_DIM / 256) * (BATCH / 16), 256, 0, stream>>>(x, gT, rT, rsp, A, out);
  build_W_k<<<(OUT_DIM * (KDIM / 4)) / 256, 256, 0, stream>>>(coeffs, bw, W);
  gemm_k<<<256 * KSPLIT, 256, 0, stream>>>(A, W, out);
}